// Round 4
// baseline (716.110 us; speedup 1.0000x reference)
//
#include <hip/hip_runtime.h>

#define N_NODES 100000
#define N_EDGES 1600000
#define D 128
#define EPS 1e-5f

#define NPB_BITS 7
#define NODES_PER_BUCK 128
#define NBUCK ((N_NODES + NODES_PER_BUCK - 1) >> NPB_BITS)   // 782
#define BUCK_CAP 4096    // LDS edge cache per bucket (avg 2046, ~max 2400)

typedef unsigned int uint;
typedef unsigned short ushort;
using bf16x8 = __attribute__((ext_vector_type(8))) short;
using f32x4  = __attribute__((ext_vector_type(4))) float;

__device__ __forceinline__ ushort f2bf(float f) {
    uint u = __float_as_uint(f);
    return (ushort)((u + 0x7fffu + ((u >> 16) & 1u)) >> 16);   // RNE
}
__device__ __forceinline__ float bflo(uint u) { return __uint_as_float(u << 16); }
__device__ __forceinline__ float bfhi(uint u) { return __uint_as_float(u & 0xffff0000u); }

// ---------------- bucketed CSR build ----------------

// P1: bucket histogram, LDS-aggregated
__global__ __launch_bounds__(256) void k_bhist(const int* __restrict__ ei, int* __restrict__ bcnt) {
    __shared__ int sc[NBUCK];
    int t = threadIdx.x;
    for (int i = t; i < NBUCK; i += 256) sc[i] = 0;
    __syncthreads();
    int stride = gridDim.x * 256;
    for (int e = blockIdx.x * 256 + t; e < N_EDGES; e += stride)
        atomicAdd(&sc[ei[N_EDGES + e] >> NPB_BITS], 1);
    __syncthreads();
    for (int i = t; i < NBUCK; i += 256) {
        int v = sc[i];
        if (v) atomicAdd(&bcnt[i], v);
    }
}

// P2: exclusive scan of 782 bucket counts (one block of 1024)
__global__ __launch_bounds__(1024) void k_bscan(const int* __restrict__ bcnt,
                                                int* __restrict__ bstart, int* __restrict__ bcur,
                                                int* __restrict__ row_start) {
    __shared__ int s[1024];
    int t = threadIdx.x;
    int own = (t < NBUCK) ? bcnt[t] : 0;
    s[t] = own;
    __syncthreads();
    for (int off = 1; off < 1024; off <<= 1) {
        int v = (t >= off) ? s[t - off] : 0;
        __syncthreads();
        s[t] += v;
        __syncthreads();
    }
    if (t < NBUCK) {
        int excl = s[t] - own;
        bstart[t] = excl;
        bcur[t] = excl;
    }
    if (t == 0) {
        bstart[NBUCK] = N_EDGES;
        row_start[N_NODES] = N_EDGES;
    }
}

// P3: bin edges into bucket regions, packed (src<<7)|dst_local
__global__ __launch_bounds__(256) void k_bin(const int* __restrict__ ei, int* __restrict__ bcur,
                                             uint* __restrict__ binned) {
    int e = blockIdx.x * 256 + threadIdx.x;
    if (e < N_EDGES) {
        int s = ei[e];
        int d = ei[N_EDGES + e];
        int b = d >> NPB_BITS;
        int pos = atomicAdd(&bcur[b], 1);
        binned[pos] = ((uint)s << NPB_BITS) | (uint)(d & (NODES_PER_BUCK - 1));
    }
}

// P4: per-bucket local CSR (counts -> scan -> scatter), contiguous writes
__global__ __launch_bounds__(256) void k_bcsr(const uint* __restrict__ binned,
                                              const int* __restrict__ bstart,
                                              int* __restrict__ row_start,
                                              int* __restrict__ csr_src) {
    __shared__ int cnt[NODES_PER_BUCK];
    __shared__ int sc[NODES_PER_BUCK];
    __shared__ int cur[NODES_PER_BUCK];
    __shared__ uint ecache[BUCK_CAP];
    int b = blockIdx.x, t = threadIdx.x;
    int s0 = bstart[b], s1 = bstart[b + 1];
    if (t < NODES_PER_BUCK) cnt[t] = 0;
    __syncthreads();
    for (int e = s0 + t; e < s1; e += 256) {
        uint u = binned[e];
        int idx = e - s0;
        if (idx < BUCK_CAP) ecache[idx] = u;
        atomicAdd(&cnt[u & (NODES_PER_BUCK - 1)], 1);
    }
    __syncthreads();
    int own = (t < NODES_PER_BUCK) ? cnt[t] : 0;
    if (t < NODES_PER_BUCK) sc[t] = own;
    __syncthreads();
    for (int off = 1; off < NODES_PER_BUCK; off <<= 1) {
        int v = (t < NODES_PER_BUCK && t >= off) ? sc[t - off] : 0;
        __syncthreads();
        if (t < NODES_PER_BUCK) sc[t] += v;
        __syncthreads();
    }
    if (t < NODES_PER_BUCK) {
        int excl = s0 + sc[t] - own;
        int node = (b << NPB_BITS) + t;
        if (node < N_NODES) row_start[node] = excl;
        cur[t] = excl;
    }
    __syncthreads();
    for (int e = s0 + t; e < s1; e += 256) {
        int idx = e - s0;
        uint u = (idx < BUCK_CAP) ? ecache[idx] : binned[e];
        int pos = atomicAdd(&cur[u & (NODES_PER_BUCK - 1)], 1);
        csr_src[pos] = (int)(u >> NPB_BITS);
    }
}

// ---------------- weight cast ----------------

__global__ void k_cast_w(const float* __restrict__ Wl, const float* __restrict__ Wr,
                         ushort* __restrict__ W2, int dout) {
    int i = blockIdx.x * blockDim.x + threadIdx.x;
    int total = 2 * dout * D;
    if (i < total) {
        int o = i >> 7, k = i & 127;
        float v = (o < dout) ? Wl[o * D + k] : Wr[(o - dout) * D + k];
        W2[i] = f2bf(v);
    }
}

// ---------------- MFMA dual GEMM ----------------
// Z = X@Wl^T, Y = X@Wr^T + b, both bf16 out. X: [N][128] (bf16 or f32).
// W2: [2*DOUT][128] bf16 (Wl rows then Wr rows).
// Block: 256 thr (4 waves) x 64-row tile. Wave w owns rows 16w..16w+15.
template <int DOUT, bool IN_F32>
__global__ __launch_bounds__(256) void k_gemm_mfma(
    const void* __restrict__ Xv, const ushort* __restrict__ W2,
    const float* __restrict__ bias,
    ushort* __restrict__ Zb, ushort* __restrict__ Yb) {
    constexpr int NT = 2 * DOUT;       // 256 or 128 outputs
    constexpr int OT = NT / 16;        // 16 or 8 otiles

    __shared__ ushort sW[OT * 4 * 64 * 8];   // 64 KB / 32 KB, fragment order

    int t = threadIdx.x;
    int n0 = blockIdx.x * 64;

    int w = t >> 6, l = t & 63;
    int arow = n0 + 16 * w + (l & 15);
    if (arow >= N_NODES) arow = N_NODES - 1;
    bf16x8 afr[4];
    if (IN_F32) {
        const float* ap = &((const float*)Xv)[(size_t)arow * D + ((l >> 4) * 8)];
#pragma unroll
        for (int kt = 0; kt < 4; ++kt) {
            float4 v0 = *(const float4*)(ap + kt * 32);
            float4 v1 = *(const float4*)(ap + kt * 32 + 4);
            bf16x8 f;
            f[0] = (short)f2bf(v0.x); f[1] = (short)f2bf(v0.y);
            f[2] = (short)f2bf(v0.z); f[3] = (short)f2bf(v0.w);
            f[4] = (short)f2bf(v1.x); f[5] = (short)f2bf(v1.y);
            f[6] = (short)f2bf(v1.z); f[7] = (short)f2bf(v1.w);
            afr[kt] = f;
        }
    } else {
        const ushort* ap = &((const ushort*)Xv)[(size_t)arow * D + ((l >> 4) * 8)];
#pragma unroll
        for (int kt = 0; kt < 4; ++kt) afr[kt] = *(const bf16x8*)(ap + kt * 32);
    }

    // stage W fragments: slot s -> frag f = s>>6, lane = s&63
    // element: o = (f>>2)*16 + (lane&15), k = (f&3)*32 + (lane>>4)*8
    for (int s = t; s < OT * 4 * 64; s += 256) {
        int f = s >> 6, ln = s & 63;
        int o = (f >> 2) * 16 + (ln & 15);
        int k = (f & 3) * 32 + ((ln >> 4) * 8);
        *(uint4*)&sW[s * 8] = *(const uint4*)&W2[o * D + k];
    }
    __syncthreads();

    f32x4 acc[OT];
#pragma unroll
    for (int ot = 0; ot < OT; ++ot) acc[ot] = (f32x4){0.f, 0.f, 0.f, 0.f};

#pragma unroll
    for (int kt = 0; kt < 4; ++kt) {
#pragma unroll
        for (int ot = 0; ot < OT; ++ot) {
            bf16x8 bfr = *(const bf16x8*)&sW[((ot * 4 + kt) * 64 + l) * 8];
            acc[ot] = __builtin_amdgcn_mfma_f32_16x16x32_bf16(afr[kt], bfr, acc[ot], 0, 0, 0);
        }
    }
    __syncthreads();

    // dump acc to LDS as f32 [64][NT]; C map: row=(l>>4)*4+j, col=l&15
    float* sC = (float*)sW;
    int r0 = (l >> 4) * 4;
#pragma unroll
    for (int ot = 0; ot < OT; ++ot)
#pragma unroll
        for (int j = 0; j < 4; ++j)
            sC[(16 * w + r0 + j) * NT + ot * 16 + (l & 15)] = acc[ot][j];
    __syncthreads();

    // pack both halves to bf16: Z cols [0,DOUT), Y cols [DOUT,2*DOUT)+bias
    constexpr int CH = NT / 8;         // ushort8 chunks per row: 32 or 16
    for (int c = t; c < 64 * CH; c += 256) {
        int r = c / CH, cc = (c % CH) * 8;
        if (n0 + r >= N_NODES) continue;
        bool isY = cc >= DOUT;
        uint4 pk;
        uint* pw = (uint*)&pk;
#pragma unroll
        for (int j = 0; j < 4; ++j) {
            float f0 = sC[r * NT + cc + 2 * j];
            float f1 = sC[r * NT + cc + 2 * j + 1];
            if (isY) {
                f0 += bias[cc - DOUT + 2 * j];
                f1 += bias[cc - DOUT + 2 * j + 1];
            }
            pw[j] = (uint)f2bf(f0) | ((uint)f2bf(f1) << 16);
        }
        if (isY) *(uint4*)&Yb[(size_t)(n0 + r) * DOUT + cc - DOUT] = pk;
        else     *(uint4*)&Zb[(size_t)(n0 + r) * DOUT + cc] = pk;
    }
}

// ---------------- mean aggregation + epilogue ----------------
// H[n][c] = Y[n][c] + mean_e Z[src(e)][c]; optional BN+ReLU.
template <int DOUT, bool BNRELU, bool OUT_BF16>
__global__ __launch_bounds__(64) void k_agg(
    const ushort* __restrict__ Zb, const int* __restrict__ row_start,
    const int* __restrict__ csr_src,
    const float* __restrict__ gamma, const float* __restrict__ beta,
    const float* __restrict__ mean, const float* __restrict__ var,
    const ushort* __restrict__ Yb, void* __restrict__ Hout) {
    constexpr int LG = DOUT / 2;          // lanes per node: 64 or 32
    constexpr int NPB = 64 / LG;          // nodes per block: 1 or 2
    int t = threadIdx.x;
    int sub = t / LG, tt = t % LG;
    int n = blockIdx.x * NPB + sub;
    int s0 = row_start[n], s1 = row_start[n + 1];
    int c2 = tt * 2;
    float a0 = 0.f, a1 = 0.f;
    int e = s0;
    for (; e + 4 <= s1; e += 4) {
        int i0 = csr_src[e], i1 = csr_src[e + 1], i2 = csr_src[e + 2], i3 = csr_src[e + 3];
        uint u0 = *(const uint*)&Zb[(size_t)i0 * DOUT + c2];
        uint u1 = *(const uint*)&Zb[(size_t)i1 * DOUT + c2];
        uint u2 = *(const uint*)&Zb[(size_t)i2 * DOUT + c2];
        uint u3 = *(const uint*)&Zb[(size_t)i3 * DOUT + c2];
        a0 += bflo(u0) + bflo(u1) + bflo(u2) + bflo(u3);
        a1 += bfhi(u0) + bfhi(u1) + bfhi(u2) + bfhi(u3);
    }
    for (; e < s1; ++e) {
        uint u = *(const uint*)&Zb[(size_t)csr_src[e] * DOUT + c2];
        a0 += bflo(u);
        a1 += bfhi(u);
    }
    float inv = 1.f / fmaxf((float)(s1 - s0), 1.f);
    size_t base = (size_t)n * DOUT + c2;
    uint uy = *(const uint*)&Yb[base];
    float h0 = bflo(uy) + a0 * inv;
    float h1 = bfhi(uy) + a1 * inv;
    if (BNRELU) {
        h0 = fmaxf((h0 - mean[c2]) * (gamma[c2] * rsqrtf(var[c2] + EPS)) + beta[c2], 0.f);
        h1 = fmaxf((h1 - mean[c2 + 1]) * (gamma[c2 + 1] * rsqrtf(var[c2 + 1] + EPS)) + beta[c2 + 1], 0.f);
    }
    if (OUT_BF16) {
        uint pk = (uint)f2bf(h0) | ((uint)f2bf(h1) << 16);
        *(uint*)&((ushort*)Hout)[base] = pk;
    } else {
        float2 o; o.x = h0; o.y = h1;
        *(float2*)&((float*)Hout)[base] = o;
    }
}

// ---------------- launch ----------------

static inline size_t align256(size_t x) { return (x + 255) & ~(size_t)255; }

extern "C" void kernel_launch(void* const* d_in, const int* in_sizes, int n_in,
                              void* d_out, int out_size, void* d_ws, size_t ws_size,
                              hipStream_t stream) {
    const float* x    = (const float*)d_in[0];
    const int*   ei   = (const int*)d_in[1];      // int32 (JAX default int)
    const float* w_l1 = (const float*)d_in[2];
    const float* b_l1 = (const float*)d_in[3];
    const float* w_r1 = (const float*)d_in[4];
    const float* g1   = (const float*)d_in[5];
    const float* be1  = (const float*)d_in[6];
    const float* m1   = (const float*)d_in[7];
    const float* v1   = (const float*)d_in[8];
    const float* w_l2 = (const float*)d_in[9];
    const float* b_l2 = (const float*)d_in[10];
    const float* w_r2 = (const float*)d_in[11];
    const float* g2   = (const float*)d_in[12];
    const float* be2  = (const float*)d_in[13];
    const float* m2   = (const float*)d_in[14];
    const float* v2   = (const float*)d_in[15];
    const float* w_l3 = (const float*)d_in[16];
    const float* b_l3 = (const float*)d_in[17];
    const float* w_r3 = (const float*)d_in[18];
    float* out = (float*)d_out;

    char* w = (char*)d_ws;
    int* bcnt      = (int*)w;  w += align256((size_t)NBUCK * 4);
    int* bstart    = (int*)w;  w += align256((size_t)(NBUCK + 1) * 4);
    int* bcur      = (int*)w;  w += align256((size_t)NBUCK * 4);
    uint* binned   = (uint*)w; w += align256((size_t)N_EDGES * 4);
    int* row_start = (int*)w;  w += align256((size_t)(N_NODES + 1) * 4);
    int* csr_src   = (int*)w;  w += align256((size_t)N_EDGES * 4);
    ushort* hb     = (ushort*)w; w += align256((size_t)N_NODES * D * 2);
    ushort* Zb     = (ushort*)w; w += align256((size_t)N_NODES * D * 2);
    ushort* Yb     = (ushort*)w; w += align256((size_t)N_NODES * D * 2);
    ushort* w2_1   = (ushort*)w; w += align256((size_t)2 * D * D * 2);
    ushort* w2_2   = (ushort*)w; w += align256((size_t)2 * D * D * 2);
    ushort* w2_3   = (ushort*)w; w += align256((size_t)D * D * 2);

    hipMemsetAsync(bcnt, 0, (size_t)NBUCK * 4, stream);

    // CSR build
    k_bhist<<<256, 256, 0, stream>>>(ei, bcnt);
    k_bscan<<<1, 1024, 0, stream>>>(bcnt, bstart, bcur, row_start);
    int eb = (N_EDGES + 255) / 256;
    k_bin<<<eb, 256, 0, stream>>>(ei, bcur, binned);
    k_bcsr<<<NBUCK, 256, 0, stream>>>(binned, bstart, row_start, csr_src);

    // weight casts
    k_cast_w<<<(2 * D * D + 255) / 256, 256, 0, stream>>>(w_l1, w_r1, w2_1, D);
    k_cast_w<<<(2 * D * D + 255) / 256, 256, 0, stream>>>(w_l2, w_r2, w2_2, D);
    k_cast_w<<<(D * D + 255) / 256, 256, 0, stream>>>(w_l3, w_r3, w2_3, 64);

    int gb = (N_NODES + 63) / 64;   // 1563

    // layer 1 (reads f32 x directly)
    k_gemm_mfma<128, true><<<gb, 256, 0, stream>>>(x, w2_1, b_l1, Zb, Yb);
    k_agg<128, true, true><<<N_NODES, 64, 0, stream>>>(Zb, row_start, csr_src, g1, be1, m1, v1, Yb, hb);
    // layer 2
    k_gemm_mfma<128, false><<<gb, 256, 0, stream>>>(hb, w2_2, b_l2, Zb, Yb);
    k_agg<128, true, true><<<N_NODES, 64, 0, stream>>>(Zb, row_start, csr_src, g2, be2, m2, v2, Yb, hb);
    // layer 3
    k_gemm_mfma<64, false><<<gb, 256, 0, stream>>>(hb, w2_3, b_l3, Zb, Yb);
    k_agg<64, false, false><<<N_NODES / 2, 64, 0, stream>>>(Zb, row_start, csr_src, b_l3, b_l3, b_l3, b_l3, Yb, out);
}

// Round 5
// 365.555 us; speedup vs baseline: 1.9590x; 1.9590x over previous
//
#include <hip/hip_runtime.h>

#define N_NODES 100000
#define N_EDGES 1600000
#define D 128
#define EPS 1e-5f

#define NPB_BITS 8
#define NODES_PER_BUCK 256
#define NBUCK ((N_NODES + NODES_PER_BUCK - 1) >> NPB_BITS)   // 391
#define BUCK_CAP 5120    // LDS edge cache per bucket (avg 4092, +5sd ~4400)

#define CHUNK_E 8192
#define NB_BIN ((N_EDGES + CHUNK_E - 1) / CHUNK_E)           // 196

typedef unsigned int uint;
typedef unsigned short ushort;
using bf16x8 = __attribute__((ext_vector_type(8))) short;
using f32x4  = __attribute__((ext_vector_type(4))) float;

__device__ __forceinline__ ushort f2bf(float f) {
    uint u = __float_as_uint(f);
    return (ushort)((u + 0x7fffu + ((u >> 16) & 1u)) >> 16);   // RNE
}
__device__ __forceinline__ float bflo(uint u) { return __uint_as_float(u << 16); }
__device__ __forceinline__ float bfhi(uint u) { return __uint_as_float(u & 0xffff0000u); }

// ---------------- bucketed CSR build ----------------

// P1: bucket histogram, LDS-privatized
__global__ __launch_bounds__(256) void k_bhist(const int* __restrict__ ei, int* __restrict__ bcnt) {
    __shared__ int sc[NBUCK];
    int t = threadIdx.x;
    for (int i = t; i < NBUCK; i += 256) sc[i] = 0;
    __syncthreads();
    int stride = gridDim.x * 256;
    for (int e = blockIdx.x * 256 + t; e < N_EDGES; e += stride)
        atomicAdd(&sc[ei[N_EDGES + e] >> NPB_BITS], 1);
    __syncthreads();
    for (int i = t; i < NBUCK; i += 256) {
        int v = sc[i];
        if (v) atomicAdd(&bcnt[i], v);
    }
}

// P2: exclusive scan of bucket counts (one block of 1024)
__global__ __launch_bounds__(1024) void k_bscan(const int* __restrict__ bcnt,
                                                int* __restrict__ bstart, int* __restrict__ bcur,
                                                int* __restrict__ row_start) {
    __shared__ int s[1024];
    int t = threadIdx.x;
    int own = (t < NBUCK) ? bcnt[t] : 0;
    s[t] = own;
    __syncthreads();
    for (int off = 1; off < 1024; off <<= 1) {
        int v = (t >= off) ? s[t - off] : 0;
        __syncthreads();
        s[t] += v;
        __syncthreads();
    }
    if (t < NBUCK) {
        int excl = s[t] - own;
        bstart[t] = excl;
        bcur[t] = excl;
    }
    if (t == 0) {
        bstart[NBUCK] = N_EDGES;
        row_start[N_NODES] = N_EDGES;
    }
}

// P3: privatized binning. Per block: LDS histogram of its chunk -> one global
// atomicAdd per touched bucket (range reservation) -> LDS-cursor scatter.
__global__ __launch_bounds__(256) void k_bin2(const int* __restrict__ ei,
                                              int* __restrict__ bcur,
                                              uint* __restrict__ binned) {
    __shared__ int cnt[NBUCK];
    __shared__ int base[NBUCK];
    int t = threadIdx.x;
    int e0 = blockIdx.x * CHUNK_E;
    int e1 = e0 + CHUNK_E; if (e1 > N_EDGES) e1 = N_EDGES;
    for (int i = t; i < NBUCK; i += 256) cnt[i] = 0;
    __syncthreads();
    for (int e = e0 + t; e < e1; e += 256)
        atomicAdd(&cnt[ei[N_EDGES + e] >> NPB_BITS], 1);
    __syncthreads();
    for (int i = t; i < NBUCK; i += 256) {
        int v = cnt[i];
        base[i] = v ? atomicAdd(&bcur[i], v) : 0;
        cnt[i] = 0;               // reuse as local cursor
    }
    __syncthreads();
    for (int e = e0 + t; e < e1; e += 256) {
        int s = ei[e];
        int d = ei[N_EDGES + e];
        int b = d >> NPB_BITS;
        int pos = base[b] + atomicAdd(&cnt[b], 1);
        binned[pos] = ((uint)s << NPB_BITS) | (uint)(d & (NODES_PER_BUCK - 1));
    }
}

// P4: per-bucket local CSR (counts -> scan -> scatter), contiguous writes
__global__ __launch_bounds__(256) void k_bcsr(const uint* __restrict__ binned,
                                              const int* __restrict__ bstart,
                                              int* __restrict__ row_start,
                                              int* __restrict__ csr_src) {
    __shared__ int cnt[NODES_PER_BUCK];
    __shared__ int sc[NODES_PER_BUCK];
    __shared__ int cur[NODES_PER_BUCK];
    __shared__ uint ecache[BUCK_CAP];
    int b = blockIdx.x, t = threadIdx.x;
    int s0 = bstart[b], s1 = bstart[b + 1];
    cnt[t] = 0;
    __syncthreads();
    for (int e = s0 + t; e < s1; e += 256) {
        uint u = binned[e];
        int idx = e - s0;
        if (idx < BUCK_CAP) ecache[idx] = u;
        atomicAdd(&cnt[u & (NODES_PER_BUCK - 1)], 1);
    }
    __syncthreads();
    int own = cnt[t];
    sc[t] = own;
    __syncthreads();
    for (int off = 1; off < NODES_PER_BUCK; off <<= 1) {
        int v = (t >= off) ? sc[t - off] : 0;
        __syncthreads();
        sc[t] += v;
        __syncthreads();
    }
    {
        int excl = s0 + sc[t] - own;
        int node = (b << NPB_BITS) + t;
        if (node < N_NODES) row_start[node] = excl;
        cur[t] = excl;
    }
    __syncthreads();
    for (int e = s0 + t; e < s1; e += 256) {
        int idx = e - s0;
        uint u = (idx < BUCK_CAP) ? ecache[idx] : binned[e];
        int pos = atomicAdd(&cur[u & (NODES_PER_BUCK - 1)], 1);
        csr_src[pos] = (int)(u >> NPB_BITS);
    }
}

// ---------------- weight cast ----------------

__global__ void k_cast_w(const float* __restrict__ Wl, const float* __restrict__ Wr,
                         ushort* __restrict__ W2, int dout) {
    int i = blockIdx.x * blockDim.x + threadIdx.x;
    int total = 2 * dout * D;
    if (i < total) {
        int o = i >> 7, k = i & 127;
        float v = (o < dout) ? Wl[o * D + k] : Wr[(o - dout) * D + k];
        W2[i] = f2bf(v);
    }
}

// ---------------- MFMA dual GEMM ----------------
// Z = X@Wl^T, Y = X@Wr^T + b, both bf16 out. X: [N][128] (bf16 or f32).
// W2: [2*DOUT][128] bf16 (Wl rows then Wr rows).
// Block: 256 thr (4 waves) x 64-row tile. Wave w owns rows 16w..16w+15.
template <int DOUT, bool IN_F32>
__global__ __launch_bounds__(256) void k_gemm_mfma(
    const void* __restrict__ Xv, const ushort* __restrict__ W2,
    const float* __restrict__ bias,
    ushort* __restrict__ Zb, ushort* __restrict__ Yb) {
    constexpr int NT = 2 * DOUT;       // 256 or 128 outputs
    constexpr int OT = NT / 16;        // 16 or 8 otiles

    __shared__ ushort sW[OT * 4 * 64 * 8];   // 64 KB / 32 KB, fragment order

    int t = threadIdx.x;
    int n0 = blockIdx.x * 64;

    int w = t >> 6, l = t & 63;
    int arow = n0 + 16 * w + (l & 15);
    if (arow >= N_NODES) arow = N_NODES - 1;
    bf16x8 afr[4];
    if (IN_F32) {
        const float* ap = &((const float*)Xv)[(size_t)arow * D + ((l >> 4) * 8)];
#pragma unroll
        for (int kt = 0; kt < 4; ++kt) {
            float4 v0 = *(const float4*)(ap + kt * 32);
            float4 v1 = *(const float4*)(ap + kt * 32 + 4);
            bf16x8 f;
            f[0] = (short)f2bf(v0.x); f[1] = (short)f2bf(v0.y);
            f[2] = (short)f2bf(v0.z); f[3] = (short)f2bf(v0.w);
            f[4] = (short)f2bf(v1.x); f[5] = (short)f2bf(v1.y);
            f[6] = (short)f2bf(v1.z); f[7] = (short)f2bf(v1.w);
            afr[kt] = f;
        }
    } else {
        const ushort* ap = &((const ushort*)Xv)[(size_t)arow * D + ((l >> 4) * 8)];
#pragma unroll
        for (int kt = 0; kt < 4; ++kt) afr[kt] = *(const bf16x8*)(ap + kt * 32);
    }

    // stage W fragments: slot s -> frag f = s>>6, lane = s&63
    // element: o = (f>>2)*16 + (lane&15), k = (f&3)*32 + (lane>>4)*8
    for (int s = t; s < OT * 4 * 64; s += 256) {
        int f = s >> 6, ln = s & 63;
        int o = (f >> 2) * 16 + (ln & 15);
        int k = (f & 3) * 32 + ((ln >> 4) * 8);
        *(uint4*)&sW[s * 8] = *(const uint4*)&W2[o * D + k];
    }
    __syncthreads();

    f32x4 acc[OT];
#pragma unroll
    for (int ot = 0; ot < OT; ++ot) acc[ot] = (f32x4){0.f, 0.f, 0.f, 0.f};

#pragma unroll
    for (int kt = 0; kt < 4; ++kt) {
#pragma unroll
        for (int ot = 0; ot < OT; ++ot) {
            bf16x8 bfr = *(const bf16x8*)&sW[((ot * 4 + kt) * 64 + l) * 8];
            acc[ot] = __builtin_amdgcn_mfma_f32_16x16x32_bf16(afr[kt], bfr, acc[ot], 0, 0, 0);
        }
    }
    __syncthreads();

    // dump acc to LDS as f32 [64][NT]; C map: row=(l>>4)*4+j, col=l&15
    float* sC = (float*)sW;
    int r0 = (l >> 4) * 4;
#pragma unroll
    for (int ot = 0; ot < OT; ++ot)
#pragma unroll
        for (int j = 0; j < 4; ++j)
            sC[(16 * w + r0 + j) * NT + ot * 16 + (l & 15)] = acc[ot][j];
    __syncthreads();

    // pack both halves to bf16: Z cols [0,DOUT), Y cols [DOUT,2*DOUT)+bias
    constexpr int CH = NT / 8;         // ushort8 chunks per row: 32 or 16
    for (int c = t; c < 64 * CH; c += 256) {
        int r = c / CH, cc = (c % CH) * 8;
        if (n0 + r >= N_NODES) continue;
        bool isY = cc >= DOUT;
        uint4 pk;
        uint* pw = (uint*)&pk;
#pragma unroll
        for (int j = 0; j < 4; ++j) {
            float f0 = sC[r * NT + cc + 2 * j];
            float f1 = sC[r * NT + cc + 2 * j + 1];
            if (isY) {
                f0 += bias[cc - DOUT + 2 * j];
                f1 += bias[cc - DOUT + 2 * j + 1];
            }
            pw[j] = (uint)f2bf(f0) | ((uint)f2bf(f1) << 16);
        }
        if (isY) *(uint4*)&Yb[(size_t)(n0 + r) * DOUT + cc - DOUT] = pk;
        else     *(uint4*)&Zb[(size_t)(n0 + r) * DOUT + cc] = pk;
    }
}

// ---------------- mean aggregation + epilogue ----------------
// H[n][c] = Y[n][c] + mean_e Z[src(e)][c]; optional BN+ReLU.
template <int DOUT, bool BNRELU, bool OUT_BF16>
__global__ __launch_bounds__(64) void k_agg(
    const ushort* __restrict__ Zb, const int* __restrict__ row_start,
    const int* __restrict__ csr_src,
    const float* __restrict__ gamma, const float* __restrict__ beta,
    const float* __restrict__ mean, const float* __restrict__ var,
    const ushort* __restrict__ Yb, void* __restrict__ Hout) {
    constexpr int LG = DOUT / 2;          // lanes per node: 64 or 32
    constexpr int NPB = 64 / LG;          // nodes per block: 1 or 2
    int t = threadIdx.x;
    int sub = t / LG, tt = t % LG;
    int n = blockIdx.x * NPB + sub;
    int s0 = row_start[n], s1 = row_start[n + 1];
    int c2 = tt * 2;
    float a0 = 0.f, a1 = 0.f;
    int e = s0;
    for (; e + 4 <= s1; e += 4) {
        int i0 = csr_src[e], i1 = csr_src[e + 1], i2 = csr_src[e + 2], i3 = csr_src[e + 3];
        uint u0 = *(const uint*)&Zb[(size_t)i0 * DOUT + c2];
        uint u1 = *(const uint*)&Zb[(size_t)i1 * DOUT + c2];
        uint u2 = *(const uint*)&Zb[(size_t)i2 * DOUT + c2];
        uint u3 = *(const uint*)&Zb[(size_t)i3 * DOUT + c2];
        a0 += bflo(u0) + bflo(u1) + bflo(u2) + bflo(u3);
        a1 += bfhi(u0) + bfhi(u1) + bfhi(u2) + bfhi(u3);
    }
    for (; e < s1; ++e) {
        uint u = *(const uint*)&Zb[(size_t)csr_src[e] * DOUT + c2];
        a0 += bflo(u);
        a1 += bfhi(u);
    }
    float inv = 1.f / fmaxf((float)(s1 - s0), 1.f);
    size_t base = (size_t)n * DOUT + c2;
    uint uy = *(const uint*)&Yb[base];
    float h0 = bflo(uy) + a0 * inv;
    float h1 = bfhi(uy) + a1 * inv;
    if (BNRELU) {
        h0 = fmaxf((h0 - mean[c2]) * (gamma[c2] * rsqrtf(var[c2] + EPS)) + beta[c2], 0.f);
        h1 = fmaxf((h1 - mean[c2 + 1]) * (gamma[c2 + 1] * rsqrtf(var[c2 + 1] + EPS)) + beta[c2 + 1], 0.f);
    }
    if (OUT_BF16) {
        uint pk = (uint)f2bf(h0) | ((uint)f2bf(h1) << 16);
        *(uint*)&((ushort*)Hout)[base] = pk;
    } else {
        float2 o; o.x = h0; o.y = h1;
        *(float2*)&((float*)Hout)[base] = o;
    }
}

// ---------------- launch ----------------

static inline size_t align256(size_t x) { return (x + 255) & ~(size_t)255; }

extern "C" void kernel_launch(void* const* d_in, const int* in_sizes, int n_in,
                              void* d_out, int out_size, void* d_ws, size_t ws_size,
                              hipStream_t stream) {
    const float* x    = (const float*)d_in[0];
    const int*   ei   = (const int*)d_in[1];      // int32 (JAX default int)
    const float* w_l1 = (const float*)d_in[2];
    const float* b_l1 = (const float*)d_in[3];
    const float* w_r1 = (const float*)d_in[4];
    const float* g1   = (const float*)d_in[5];
    const float* be1  = (const float*)d_in[6];
    const float* m1   = (const float*)d_in[7];
    const float* v1   = (const float*)d_in[8];
    const float* w_l2 = (const float*)d_in[9];
    const float* b_l2 = (const float*)d_in[10];
    const float* w_r2 = (const float*)d_in[11];
    const float* g2   = (const float*)d_in[12];
    const float* be2  = (const float*)d_in[13];
    const float* m2   = (const float*)d_in[14];
    const float* v2   = (const float*)d_in[15];
    const float* w_l3 = (const float*)d_in[16];
    const float* b_l3 = (const float*)d_in[17];
    const float* w_r3 = (const float*)d_in[18];
    float* out = (float*)d_out;

    char* w = (char*)d_ws;
    int* bcnt      = (int*)w;  w += align256((size_t)NBUCK * 4);
    int* bstart    = (int*)w;  w += align256((size_t)(NBUCK + 1) * 4);
    int* bcur      = (int*)w;  w += align256((size_t)NBUCK * 4);
    uint* binned   = (uint*)w; w += align256((size_t)N_EDGES * 4);
    int* row_start = (int*)w;  w += align256((size_t)(N_NODES + 1) * 4);
    int* csr_src   = (int*)w;  w += align256((size_t)N_EDGES * 4);
    ushort* hb     = (ushort*)w; w += align256((size_t)N_NODES * D * 2);
    ushort* Zb     = (ushort*)w; w += align256((size_t)N_NODES * D * 2);
    ushort* Yb     = (ushort*)w; w += align256((size_t)N_NODES * D * 2);
    ushort* w2_1   = (ushort*)w; w += align256((size_t)2 * D * D * 2);
    ushort* w2_2   = (ushort*)w; w += align256((size_t)2 * D * D * 2);
    ushort* w2_3   = (ushort*)w; w += align256((size_t)D * D * 2);

    hipMemsetAsync(bcnt, 0, (size_t)NBUCK * 4, stream);

    // CSR build
    k_bhist<<<256, 256, 0, stream>>>(ei, bcnt);
    k_bscan<<<1, 1024, 0, stream>>>(bcnt, bstart, bcur, row_start);
    k_bin2<<<NB_BIN, 256, 0, stream>>>(ei, bcur, binned);
    k_bcsr<<<NBUCK, 256, 0, stream>>>(binned, bstart, row_start, csr_src);

    // weight casts
    k_cast_w<<<(2 * D * D + 255) / 256, 256, 0, stream>>>(w_l1, w_r1, w2_1, D);
    k_cast_w<<<(2 * D * D + 255) / 256, 256, 0, stream>>>(w_l2, w_r2, w2_2, D);
    k_cast_w<<<(D * D + 255) / 256, 256, 0, stream>>>(w_l3, w_r3, w2_3, 64);

    int gb = (N_NODES + 63) / 64;   // 1563

    // layer 1 (reads f32 x directly)
    k_gemm_mfma<128, true><<<gb, 256, 0, stream>>>(x, w2_1, b_l1, Zb, Yb);
    k_agg<128, true, true><<<N_NODES, 64, 0, stream>>>(Zb, row_start, csr_src, g1, be1, m1, v1, Yb, hb);
    // layer 2
    k_gemm_mfma<128, false><<<gb, 256, 0, stream>>>(hb, w2_2, b_l2, Zb, Yb);
    k_agg<128, true, true><<<N_NODES, 64, 0, stream>>>(Zb, row_start, csr_src, g2, be2, m2, v2, Yb, hb);
    // layer 3
    k_gemm_mfma<64, false><<<gb, 256, 0, stream>>>(hb, w2_3, b_l3, Zb, Yb);
    k_agg<64, false, false><<<N_NODES / 2, 64, 0, stream>>>(Zb, row_start, csr_src, b_l3, b_l3, b_l3, b_l3, Yb, out);
}

// Round 6
// 344.472 us; speedup vs baseline: 2.0789x; 1.0612x over previous
//
#include <hip/hip_runtime.h>

#define N_NODES 100000
#define N_EDGES 1600000
#define D 128
#define EPS 1e-5f

#define NPB_BITS 8
#define NODES_PER_BUCK 256
#define NBUCK ((N_NODES + NODES_PER_BUCK - 1) >> NPB_BITS)   // 391
#define BUCK_CAP 5120

#define CHUNK_E 8192
#define NB_BIN ((N_EDGES + CHUNK_E - 1) / CHUNK_E)           // 196

typedef unsigned int uint;
typedef unsigned short ushort;
using bf16x8 = __attribute__((ext_vector_type(8))) short;
using f32x4  = __attribute__((ext_vector_type(4))) float;

__device__ __forceinline__ ushort f2bf(float f) {
    uint u = __float_as_uint(f);
    return (ushort)((u + 0x7fffu + ((u >> 16) & 1u)) >> 16);   // RNE
}
__device__ __forceinline__ float bflo(uint u) { return __uint_as_float(u << 16); }
__device__ __forceinline__ float bfhi(uint u) { return __uint_as_float(u & 0xffff0000u); }

// ---------------- bucketed CSR build (unchanged from R5) ----------------

__global__ __launch_bounds__(256) void k_bhist(const int* __restrict__ ei, int* __restrict__ bcnt) {
    __shared__ int sc[NBUCK];
    int t = threadIdx.x;
    for (int i = t; i < NBUCK; i += 256) sc[i] = 0;
    __syncthreads();
    int stride = gridDim.x * 256;
    for (int e = blockIdx.x * 256 + t; e < N_EDGES; e += stride)
        atomicAdd(&sc[ei[N_EDGES + e] >> NPB_BITS], 1);
    __syncthreads();
    for (int i = t; i < NBUCK; i += 256) {
        int v = sc[i];
        if (v) atomicAdd(&bcnt[i], v);
    }
}

__global__ __launch_bounds__(1024) void k_bscan(const int* __restrict__ bcnt,
                                                int* __restrict__ bstart, int* __restrict__ bcur,
                                                int* __restrict__ row_start) {
    __shared__ int s[1024];
    int t = threadIdx.x;
    int own = (t < NBUCK) ? bcnt[t] : 0;
    s[t] = own;
    __syncthreads();
    for (int off = 1; off < 1024; off <<= 1) {
        int v = (t >= off) ? s[t - off] : 0;
        __syncthreads();
        s[t] += v;
        __syncthreads();
    }
    if (t < NBUCK) {
        int excl = s[t] - own;
        bstart[t] = excl;
        bcur[t] = excl;
    }
    if (t == 0) {
        bstart[NBUCK] = N_EDGES;
        row_start[N_NODES] = N_EDGES;
    }
}

__global__ __launch_bounds__(256) void k_bin2(const int* __restrict__ ei,
                                              int* __restrict__ bcur,
                                              uint* __restrict__ binned) {
    __shared__ int cnt[NBUCK];
    __shared__ int base[NBUCK];
    int t = threadIdx.x;
    int e0 = blockIdx.x * CHUNK_E;
    int e1 = e0 + CHUNK_E; if (e1 > N_EDGES) e1 = N_EDGES;
    for (int i = t; i < NBUCK; i += 256) cnt[i] = 0;
    __syncthreads();
    for (int e = e0 + t; e < e1; e += 256)
        atomicAdd(&cnt[ei[N_EDGES + e] >> NPB_BITS], 1);
    __syncthreads();
    for (int i = t; i < NBUCK; i += 256) {
        int v = cnt[i];
        base[i] = v ? atomicAdd(&bcur[i], v) : 0;
        cnt[i] = 0;
    }
    __syncthreads();
    for (int e = e0 + t; e < e1; e += 256) {
        int s = ei[e];
        int d = ei[N_EDGES + e];
        int b = d >> NPB_BITS;
        int pos = base[b] + atomicAdd(&cnt[b], 1);
        binned[pos] = ((uint)s << NPB_BITS) | (uint)(d & (NODES_PER_BUCK - 1));
    }
}

__global__ __launch_bounds__(256) void k_bcsr(const uint* __restrict__ binned,
                                              const int* __restrict__ bstart,
                                              int* __restrict__ row_start,
                                              int* __restrict__ csr_src) {
    __shared__ int cnt[NODES_PER_BUCK];
    __shared__ int sc[NODES_PER_BUCK];
    __shared__ int cur[NODES_PER_BUCK];
    __shared__ uint ecache[BUCK_CAP];
    int b = blockIdx.x, t = threadIdx.x;
    int s0 = bstart[b], s1 = bstart[b + 1];
    cnt[t] = 0;
    __syncthreads();
    for (int e = s0 + t; e < s1; e += 256) {
        uint u = binned[e];
        int idx = e - s0;
        if (idx < BUCK_CAP) ecache[idx] = u;
        atomicAdd(&cnt[u & (NODES_PER_BUCK - 1)], 1);
    }
    __syncthreads();
    int own = cnt[t];
    sc[t] = own;
    __syncthreads();
    for (int off = 1; off < NODES_PER_BUCK; off <<= 1) {
        int v = (t >= off) ? sc[t - off] : 0;
        __syncthreads();
        sc[t] += v;
        __syncthreads();
    }
    {
        int excl = s0 + sc[t] - own;
        int node = (b << NPB_BITS) + t;
        if (node < N_NODES) row_start[node] = excl;
        cur[t] = excl;
    }
    __syncthreads();
    for (int e = s0 + t; e < s1; e += 256) {
        int idx = e - s0;
        uint u = (idx < BUCK_CAP) ? ecache[idx] : binned[e];
        int pos = atomicAdd(&cur[u & (NODES_PER_BUCK - 1)], 1);
        csr_src[pos] = (int)(u >> NPB_BITS);
    }
}

// ---------------- casts / precompute ----------------

__global__ void k_cast_x(const float* __restrict__ in, ushort* __restrict__ out, int n4) {
    int i = blockIdx.x * blockDim.x + threadIdx.x;
    if (i < n4) {
        float4 v = ((const float4*)in)[i];
        ushort4 o;
        o.x = f2bf(v.x); o.y = f2bf(v.y); o.z = f2bf(v.z); o.w = f2bf(v.w);
        ((ushort4*)out)[i] = o;
    }
}

// W2 for layers 1/2: [128 out][256 k], k<128 = Wl, k>=128 = Wr
__global__ void k_cast_w12(const float* __restrict__ Wl, const float* __restrict__ Wr,
                           ushort* __restrict__ W2) {
    int i = blockIdx.x * blockDim.x + threadIdx.x;
    if (i < 128 * 256) {
        int o = i >> 8, k = i & 255;
        float v = (k < 128) ? Wl[o * 128 + k] : Wr[o * 128 + (k - 128)];
        W2[i] = f2bf(v);
    }
}

// W2 for layer 3 (old layout): [2*64 out][128 k], Wl rows then Wr rows
__global__ void k_cast_w3(const float* __restrict__ Wl, const float* __restrict__ Wr,
                          ushort* __restrict__ W2) {
    int i = blockIdx.x * blockDim.x + threadIdx.x;
    if (i < 128 * D) {
        int o = i >> 7, k = i & 127;
        float v = (o < 64) ? Wl[o * D + k] : Wr[(o - 64) * D + k];
        W2[i] = f2bf(v);
    }
}

// bnA = gamma*rsqrt(var+eps); bnB = (bias-mean)*bnA + beta
__global__ void k_bnprep(const float* __restrict__ bias, const float* __restrict__ gamma,
                         const float* __restrict__ beta, const float* __restrict__ mean,
                         const float* __restrict__ var,
                         float* __restrict__ A, float* __restrict__ B) {
    int c = threadIdx.x;
    float a = gamma[c] * rsqrtf(var[c] + EPS);
    A[c] = a;
    B[c] = (bias[c] - mean[c]) * a + beta[c];
}

// ---------------- mean gather (128 ch, bf16 -> bf16) ----------------
// 4 waves/block, 1 node/wave. Lane: g = l>>4 (edge slot), c = l&15 (8-ch group).
// Per iteration a wave consumes 4 edges, each gathered as 16B uint4 per lane.
__global__ __launch_bounds__(256) void k_agg_mean(
    const ushort* __restrict__ Zin, const int* __restrict__ row_start,
    const int* __restrict__ csr_src, ushort* __restrict__ Agg) {
    int t = threadIdx.x;
    int w = t >> 6, l = t & 63;
    int n = blockIdx.x * 4 + w;
    int g = l >> 4, c = l & 15;
    int s0 = row_start[n], s1 = row_start[n + 1];
    float a0 = 0.f, a1 = 0.f, a2 = 0.f, a3 = 0.f, a4 = 0.f, a5 = 0.f, a6 = 0.f, a7 = 0.f;
    for (int e = s0; e < s1; e += 4) {
        int ee = e + g;
        if (ee < s1) {
            int src = csr_src[ee];
            uint4 v = *(const uint4*)&Zin[(size_t)src * 128 + c * 8];
            a0 += bflo(v.x); a1 += bfhi(v.x);
            a2 += bflo(v.y); a3 += bfhi(v.y);
            a4 += bflo(v.z); a5 += bfhi(v.z);
            a6 += bflo(v.w); a7 += bfhi(v.w);
        }
    }
    // reduce across 4 edge-groups
    a0 += __shfl_xor(a0, 16); a1 += __shfl_xor(a1, 16);
    a2 += __shfl_xor(a2, 16); a3 += __shfl_xor(a3, 16);
    a4 += __shfl_xor(a4, 16); a5 += __shfl_xor(a5, 16);
    a6 += __shfl_xor(a6, 16); a7 += __shfl_xor(a7, 16);
    a0 += __shfl_xor(a0, 32); a1 += __shfl_xor(a1, 32);
    a2 += __shfl_xor(a2, 32); a3 += __shfl_xor(a3, 32);
    a4 += __shfl_xor(a4, 32); a5 += __shfl_xor(a5, 32);
    a6 += __shfl_xor(a6, 32); a7 += __shfl_xor(a7, 32);
    if (l < 16) {
        float inv = 1.f / fmaxf((float)(s1 - s0), 1.f);
        uint4 pk;
        pk.x = (uint)f2bf(a0 * inv) | ((uint)f2bf(a1 * inv) << 16);
        pk.y = (uint)f2bf(a2 * inv) | ((uint)f2bf(a3 * inv) << 16);
        pk.z = (uint)f2bf(a4 * inv) | ((uint)f2bf(a5 * inv) << 16);
        pk.w = (uint)f2bf(a6 * inv) | ((uint)f2bf(a7 * inv) << 16);
        *(uint4*)&Agg[(size_t)n * 128 + c * 8] = pk;
    }
}

// ---------------- MFMA GEMM layers 1/2 ----------------
// H = relu(bnA * (Ag@Wl^T + Xin@Wr^T) + bnB), bf16 out.
// A-row = [Ag row (k 0-127) | Xin row (k 128-255)]; W2 [128][256].
// 256 thr, 64 rows/block; two-phase 32KB weight staging; 32KB LDS total.
__global__ __launch_bounds__(256) void k_gemm12(
    const ushort* __restrict__ Ag, const ushort* __restrict__ Xin,
    const ushort* __restrict__ W2,
    const float* __restrict__ bnA, const float* __restrict__ bnB,
    ushort* __restrict__ Hout) {
    __shared__ ushort sW[16384];   // 32 KB

    int t = threadIdx.x;
    int n0 = blockIdx.x * 64;
    int w = t >> 6, l = t & 63;

    int arow = n0 + 16 * w + (l & 15);
    if (arow >= N_NODES) arow = N_NODES - 1;
    int ko = (l >> 4) * 8;
    bf16x8 afr[8];
#pragma unroll
    for (int kt = 0; kt < 4; ++kt)
        afr[kt] = *(const bf16x8*)&Ag[(size_t)arow * 128 + kt * 32 + ko];
#pragma unroll
    for (int kt = 0; kt < 4; ++kt)
        afr[4 + kt] = *(const bf16x8*)&Xin[(size_t)arow * 128 + kt * 32 + ko];

    f32x4 acc[8];
#pragma unroll
    for (int ot = 0; ot < 8; ++ot) acc[ot] = (f32x4){0.f, 0.f, 0.f, 0.f};

#pragma unroll
    for (int p = 0; p < 2; ++p) {
        // stage 32 fragments (8 ot x 4 ktl): o = ot*16+(ln&15), k = p*128+ktl*32+(ln>>4)*8
        for (int s = t; s < 2048; s += 256) {
            int f = s >> 6, ln = s & 63;
            int o = (f >> 2) * 16 + (ln & 15);
            int k = p * 128 + (f & 3) * 32 + ((ln >> 4) * 8);
            *(uint4*)&sW[s * 8] = *(const uint4*)&W2[o * 256 + k];
        }
        __syncthreads();
#pragma unroll
        for (int ktl = 0; ktl < 4; ++ktl) {
            int kt = p * 4 + ktl;
#pragma unroll
            for (int ot = 0; ot < 8; ++ot) {
                bf16x8 bfr = *(const bf16x8*)&sW[((ot * 4 + ktl) * 64 + l) * 8];
                acc[ot] = __builtin_amdgcn_mfma_f32_16x16x32_bf16(afr[kt], bfr, acc[ot], 0, 0, 0);
            }
        }
        __syncthreads();
    }

    // dump acc f32 [64][128]
    float* sC = (float*)sW;
    int r0 = (l >> 4) * 4;
#pragma unroll
    for (int ot = 0; ot < 8; ++ot)
#pragma unroll
        for (int j = 0; j < 4; ++j)
            sC[(16 * w + r0 + j) * 128 + ot * 16 + (l & 15)] = acc[ot][j];
    __syncthreads();

    // epilogue: BN+ReLU, pack bf16, 64 rows x 16 chunks of 8 ch
    for (int u = t; u < 1024; u += 256) {
        int r = u >> 4, cc = (u & 15) * 8;
        int n = n0 + r;
        if (n >= N_NODES) continue;
        float4 A0 = *(const float4*)&bnA[cc];
        float4 A1 = *(const float4*)&bnA[cc + 4];
        float4 B0 = *(const float4*)&bnB[cc];
        float4 B1 = *(const float4*)&bnB[cc + 4];
        const float* pa0 = (const float*)&A0;
        const float* pa1 = (const float*)&A1;
        const float* pb0 = (const float*)&B0;
        const float* pb1 = (const float*)&B1;
        uint4 pk;
        uint* pw = (uint*)&pk;
#pragma unroll
        for (int j = 0; j < 4; ++j) {
            int i0 = 2 * j, i1 = 2 * j + 1;
            float va = (i0 < 4) ? pa0[i0] : pa1[i0 - 4];
            float vb = (i0 < 4) ? pb0[i0] : pb1[i0 - 4];
            float wa = (i1 < 4) ? pa0[i1] : pa1[i1 - 4];
            float wb = (i1 < 4) ? pb0[i1] : pb1[i1 - 4];
            float h0 = fmaxf(sC[r * 128 + cc + i0] * va + vb, 0.f);
            float h1 = fmaxf(sC[r * 128 + cc + i1] * wa + wb, 0.f);
            pw[j] = (uint)f2bf(h0) | ((uint)f2bf(h1) << 16);
        }
        *(uint4*)&Hout[(size_t)n * 128 + cc] = pk;
    }
}

// ---------------- MFMA dual GEMM layer 3 (Z=X@Wl^T, Y=X@Wr^T+b, bf16) ----------------
__global__ __launch_bounds__(256) void k_gemm3(
    const ushort* __restrict__ Xb, const ushort* __restrict__ W2,
    const float* __restrict__ bias,
    ushort* __restrict__ Zb, ushort* __restrict__ Yb) {
    constexpr int DOUT = 64;
    constexpr int NT = 128;
    constexpr int OT = 8;

    __shared__ ushort sW[OT * 4 * 64 * 8];   // 32 KB

    int t = threadIdx.x;
    int n0 = blockIdx.x * 64;
    int w = t >> 6, l = t & 63;
    int arow = n0 + 16 * w + (l & 15);
    if (arow >= N_NODES) arow = N_NODES - 1;
    const ushort* ap = &Xb[(size_t)arow * D + ((l >> 4) * 8)];
    bf16x8 afr[4];
#pragma unroll
    for (int kt = 0; kt < 4; ++kt) afr[kt] = *(const bf16x8*)(ap + kt * 32);

    for (int s = t; s < OT * 4 * 64; s += 256) {
        int f = s >> 6, ln = s & 63;
        int o = (f >> 2) * 16 + (ln & 15);
        int k = (f & 3) * 32 + ((ln >> 4) * 8);
        *(uint4*)&sW[s * 8] = *(const uint4*)&W2[o * D + k];
    }
    __syncthreads();

    f32x4 acc[OT];
#pragma unroll
    for (int ot = 0; ot < OT; ++ot) acc[ot] = (f32x4){0.f, 0.f, 0.f, 0.f};
#pragma unroll
    for (int kt = 0; kt < 4; ++kt)
#pragma unroll
        for (int ot = 0; ot < OT; ++ot) {
            bf16x8 bfr = *(const bf16x8*)&sW[((ot * 4 + kt) * 64 + l) * 8];
            acc[ot] = __builtin_amdgcn_mfma_f32_16x16x32_bf16(afr[kt], bfr, acc[ot], 0, 0, 0);
        }
    __syncthreads();

    float* sC = (float*)sW;
    int r0 = (l >> 4) * 4;
#pragma unroll
    for (int ot = 0; ot < OT; ++ot)
#pragma unroll
        for (int j = 0; j < 4; ++j)
            sC[(16 * w + r0 + j) * NT + ot * 16 + (l & 15)] = acc[ot][j];
    __syncthreads();

    constexpr int CH = NT / 8;
    for (int c = t; c < 64 * CH; c += 256) {
        int r = c / CH, cc = (c % CH) * 8;
        if (n0 + r >= N_NODES) continue;
        bool isY = cc >= DOUT;
        uint4 pk;
        uint* pw = (uint*)&pk;
#pragma unroll
        for (int j = 0; j < 4; ++j) {
            float f0 = sC[r * NT + cc + 2 * j];
            float f1 = sC[r * NT + cc + 2 * j + 1];
            if (isY) {
                f0 += bias[cc - DOUT + 2 * j];
                f1 += bias[cc - DOUT + 2 * j + 1];
            }
            pw[j] = (uint)f2bf(f0) | ((uint)f2bf(f1) << 16);
        }
        if (isY) *(uint4*)&Yb[(size_t)(n0 + r) * DOUT + cc - DOUT] = pk;
        else     *(uint4*)&Zb[(size_t)(n0 + r) * DOUT + cc] = pk;
    }
}

// ---------------- layer-3 aggregation: out = Y + mean Z[src], f32 ----------------
// 4 waves/block, 1 node/wave. g = l>>3 (8 edge slots), c = l&7 (8-ch group).
__global__ __launch_bounds__(256) void k_agg3(
    const ushort* __restrict__ Zb, const int* __restrict__ row_start,
    const int* __restrict__ csr_src, const ushort* __restrict__ Yb,
    float* __restrict__ out) {
    int t = threadIdx.x;
    int w = t >> 6, l = t & 63;
    int n = blockIdx.x * 4 + w;
    int g = l >> 3, c = l & 7;
    int s0 = row_start[n], s1 = row_start[n + 1];
    float a0 = 0.f, a1 = 0.f, a2 = 0.f, a3 = 0.f, a4 = 0.f, a5 = 0.f, a6 = 0.f, a7 = 0.f;
    for (int e = s0; e < s1; e += 8) {
        int ee = e + g;
        if (ee < s1) {
            int src = csr_src[ee];
            uint4 v = *(const uint4*)&Zb[(size_t)src * 64 + c * 8];
            a0 += bflo(v.x); a1 += bfhi(v.x);
            a2 += bflo(v.y); a3 += bfhi(v.y);
            a4 += bflo(v.z); a5 += bfhi(v.z);
            a6 += bflo(v.w); a7 += bfhi(v.w);
        }
    }
#pragma unroll
    for (int off = 8; off <= 32; off <<= 1) {
        a0 += __shfl_xor(a0, off); a1 += __shfl_xor(a1, off);
        a2 += __shfl_xor(a2, off); a3 += __shfl_xor(a3, off);
        a4 += __shfl_xor(a4, off); a5 += __shfl_xor(a5, off);
        a6 += __shfl_xor(a6, off); a7 += __shfl_xor(a7, off);
    }
    if (l < 8) {
        float inv = 1.f / fmaxf((float)(s1 - s0), 1.f);
        uint4 yv = *(const uint4*)&Yb[(size_t)n * 64 + c * 8];
        float4 o0, o1;
        o0.x = bflo(yv.x) + a0 * inv; o0.y = bfhi(yv.x) + a1 * inv;
        o0.z = bflo(yv.y) + a2 * inv; o0.w = bfhi(yv.y) + a3 * inv;
        o1.x = bflo(yv.z) + a4 * inv; o1.y = bfhi(yv.z) + a5 * inv;
        o1.z = bflo(yv.w) + a6 * inv; o1.w = bfhi(yv.w) + a7 * inv;
        *(float4*)&out[(size_t)n * 64 + c * 8] = o0;
        *(float4*)&out[(size_t)n * 64 + c * 8 + 4] = o1;
    }
}

// ---------------- launch ----------------

static inline size_t align256(size_t x) { return (x + 255) & ~(size_t)255; }

extern "C" void kernel_launch(void* const* d_in, const int* in_sizes, int n_in,
                              void* d_out, int out_size, void* d_ws, size_t ws_size,
                              hipStream_t stream) {
    const float* x    = (const float*)d_in[0];
    const int*   ei   = (const int*)d_in[1];      // int32 (JAX default int)
    const float* w_l1 = (const float*)d_in[2];
    const float* b_l1 = (const float*)d_in[3];
    const float* w_r1 = (const float*)d_in[4];
    const float* g1   = (const float*)d_in[5];
    const float* be1  = (const float*)d_in[6];
    const float* m1   = (const float*)d_in[7];
    const float* v1   = (const float*)d_in[8];
    const float* w_l2 = (const float*)d_in[9];
    const float* b_l2 = (const float*)d_in[10];
    const float* w_r2 = (const float*)d_in[11];
    const float* g2   = (const float*)d_in[12];
    const float* be2  = (const float*)d_in[13];
    const float* m2   = (const float*)d_in[14];
    const float* v2   = (const float*)d_in[15];
    const float* w_l3 = (const float*)d_in[16];
    const float* b_l3 = (const float*)d_in[17];
    const float* w_r3 = (const float*)d_in[18];
    float* out = (float*)d_out;

    char* w = (char*)d_ws;
    int* bcnt      = (int*)w;  w += align256((size_t)NBUCK * 4);
    int* bstart    = (int*)w;  w += align256((size_t)(NBUCK + 1) * 4);
    int* bcur      = (int*)w;  w += align256((size_t)NBUCK * 4);
    uint* binned   = (uint*)w; w += align256((size_t)N_EDGES * 4);
    int* row_start = (int*)w;  w += align256((size_t)(N_NODES + 1) * 4);
    int* csr_src   = (int*)w;  w += align256((size_t)N_EDGES * 4);
    ushort* xb     = (ushort*)w; w += align256((size_t)N_NODES * D * 2);
    ushort* ag     = (ushort*)w; w += align256((size_t)N_NODES * D * 2);
    ushort* h1     = (ushort*)w; w += align256((size_t)N_NODES * D * 2);
    ushort* h2     = (ushort*)w; w += align256((size_t)N_NODES * D * 2);
    ushort* Zb     = (ushort*)w; w += align256((size_t)N_NODES * 64 * 2);
    ushort* Yb     = (ushort*)w; w += align256((size_t)N_NODES * 64 * 2);
    ushort* w2_1   = (ushort*)w; w += align256((size_t)128 * 256 * 2);
    ushort* w2_2   = (ushort*)w; w += align256((size_t)128 * 256 * 2);
    ushort* w2_3   = (ushort*)w; w += align256((size_t)128 * 128 * 2);
    float* bnA1    = (float*)w;  w += align256(128 * 4);
    float* bnB1    = (float*)w;  w += align256(128 * 4);
    float* bnA2    = (float*)w;  w += align256(128 * 4);
    float* bnB2    = (float*)w;  w += align256(128 * 4);

    hipMemsetAsync(bcnt, 0, (size_t)NBUCK * 4, stream);

    // CSR build
    k_bhist<<<256, 256, 0, stream>>>(ei, bcnt);
    k_bscan<<<1, 1024, 0, stream>>>(bcnt, bstart, bcur, row_start);
    k_bin2<<<NB_BIN, 256, 0, stream>>>(ei, bcur, binned);
    k_bcsr<<<NBUCK, 256, 0, stream>>>(binned, bstart, row_start, csr_src);

    // casts + BN precompute
    int n4 = N_NODES * D / 4;
    k_cast_x<<<(n4 + 255) / 256, 256, 0, stream>>>(x, xb, n4);
    k_cast_w12<<<(128 * 256 + 255) / 256, 256, 0, stream>>>(w_l1, w_r1, w2_1);
    k_cast_w12<<<(128 * 256 + 255) / 256, 256, 0, stream>>>(w_l2, w_r2, w2_2);
    k_cast_w3<<<(128 * 128 + 255) / 256, 256, 0, stream>>>(w_l3, w_r3, w2_3);
    k_bnprep<<<1, 128, 0, stream>>>(b_l1, g1, be1, m1, v1, bnA1, bnB1);
    k_bnprep<<<1, 128, 0, stream>>>(b_l2, g2, be2, m2, v2, bnA2, bnB2);

    int gb = (N_NODES + 63) / 64;       // 1563
    int ab = N_NODES / 4;               // 25000

    // layer 1: aggregate-first
    k_agg_mean<<<ab, 256, 0, stream>>>(xb, row_start, csr_src, ag);
    k_gemm12<<<gb, 256, 0, stream>>>(ag, xb, w2_1, bnA1, bnB1, h1);
    // layer 2
    k_agg_mean<<<ab, 256, 0, stream>>>(h1, row_start, csr_src, ag);
    k_gemm12<<<gb, 256, 0, stream>>>(ag, h1, w2_2, bnA2, bnB2, h2);
    // layer 3: GEMM then aggregate (Z rows are 128 B)
    k_gemm3<<<gb, 256, 0, stream>>>(h2, w2_3, b_l3, Zb, Yb);
    k_agg3<<<ab, 256, 0, stream>>>(Zb, row_start, csr_src, Yb, out);
}